// Round 9
// baseline (22.365 us; speedup 1.0000x reference)
//
#include <hip/hip_runtime.h>

// MedianFilter2D: 3x3 median, reflect pad, [16,3,512,512] f32.
// Per-row horizontal sorted triple (hmin,hmed,hmax); median9 =
// med3( max3(hmin x3), med3(hmed x3), min3(hmax x3) ).
// R8: oversubscription test. Thread = 2 cols x R=8 rows (786k threads,
// 3072 blocks, 48 waves/CU of work -> residency always full + backlog),
// read amp still 1.25x. dwordx2 loads (512 B per wave-instr, coalesced).
// Depth-3 rolling load pipeline, NT stores.

constexpr int Wd = 512;
constexpr int Hd = 512;
constexpr int R  = 8;   // output rows per thread

typedef float f32x2 __attribute__((ext_vector_type(2)));

__device__ __forceinline__ float med3f(float a, float b, float c) {
    return __builtin_amdgcn_fmed3f(a, b, c);
}
__device__ __forceinline__ float min3f(float a, float b, float c) {
    return fminf(fminf(a, b), c);   // v_min3_f32
}
__device__ __forceinline__ float max3f(float a, float b, float c) {
    return fmaxf(fmaxf(a, b), c);   // v_max3_f32
}

struct Raw  { f32x2 c; float e0, e3; };      // 2 main cols + 2 edge scalars
struct Trip { float mn[2], md[2], mx[2]; };

__global__ __launch_bounds__(256, 4) void MedianFilter2D_68745246540291_kernel(
    const float* __restrict__ in, float* __restrict__ out, int total) {
    int idx = blockIdx.x * blockDim.x + threadIdx.x;
    if (idx >= total) return;

    int lane = threadIdx.x & 63;
    int cg   = idx & 255;              // column pair index (512/2 = 256)
    int w2   = cg << 1;
    int rt   = (idx >> 8) & (Hd / R - 1);
    int r0   = rt * R;
    long plane = (long)(idx >> 14);    // 256 cg x 64 row tiles = 2^14

    const float* p = in  + plane * (long)(Hd * Wd);
    float*       q = out + plane * (long)(Hd * Wd);

    auto loadraw = [&](int g) -> Raw {
        int h = (g < 0) ? 1 : ((g > Hd - 1) ? Hd - 2 : g);   // reflect rows
        const float* rp = p + (long)h * Wd;
        Raw r;
        r.c  = *reinterpret_cast<const f32x2*>(rp + w2);
        r.e0 = (lane == 0  && cg != 0)   ? rp[w2 - 1] : 0.f; // 1-lane loads
        r.e3 = (lane == 63 && cg != 255) ? rp[w2 + 2] : 0.f;
        return r;
    };
    auto mktrip = [&](Raw r) -> Trip {
        float vl = __shfl_up(r.c.y, 1);          // lane-1's col w2-1
        float vr = __shfl_down(r.c.x, 1);        // lane+1's col w2+2
        if (lane == 0)  vl = (cg == 0)   ? r.c.y : r.e0;   // reflect -1 -> 1
        if (lane == 63) vr = (cg == 255) ? r.c.x : r.e3;   // reflect 512 -> 510
        float v[4] = { vl, r.c.x, r.c.y, vr };
        Trip t;
#pragma unroll
        for (int j = 0; j < 2; ++j) {
            t.mn[j] = min3f(v[j], v[j + 1], v[j + 2]);
            t.md[j] = med3f(v[j], v[j + 1], v[j + 2]);
            t.mx[j] = max3f(v[j], v[j + 1], v[j + 2]);
        }
        return t;
    };

    // depth-3 pipeline
    Raw raw[3];
#pragma unroll
    for (int k = 0; k < 3; ++k) raw[k] = loadraw(r0 - 1 + k);

    Trip t[3];
    t[0] = mktrip(raw[0]);  raw[0] = loadraw(r0 + 2);
    t[1] = mktrip(raw[1]);  raw[1] = loadraw(r0 + 3);

#pragma unroll
    for (int i = 0; i < R; ++i) {
        const int s = (i + 2) % 3;
        t[s] = mktrip(raw[s]);                        // row r0+i+1
        if (i <= R - 4) raw[s] = loadraw(r0 + i + 4); // keep 3 rows in flight
        const Trip& a = t[i % 3];
        const Trip& b = t[(i + 1) % 3];
        const Trip& c = t[s];
        f32x2 o;
#pragma unroll
        for (int j = 0; j < 2; ++j) {
            float lo = max3f(a.mn[j], b.mn[j], c.mn[j]);
            float mi = med3f(a.md[j], b.md[j], c.md[j]);
            float hi = min3f(a.mx[j], b.mx[j], c.mx[j]);
            o[j] = med3f(lo, mi, hi);
        }
        __builtin_nontemporal_store(o, reinterpret_cast<f32x2*>(
            q + (long)(r0 + i) * Wd + w2));
    }
}

extern "C" void kernel_launch(void* const* d_in, const int* in_sizes, int n_in,
                              void* d_out, int out_size, void* d_ws, size_t ws_size,
                              hipStream_t stream) {
    const float* in = (const float*)d_in[0];
    float* out = (float*)d_out;
    int total = out_size / (2 * R);            // threads: 2 cols x R rows each
    int block = 256;
    int grid = (total + block - 1) / block;    // 3072 blocks
    MedianFilter2D_68745246540291_kernel<<<grid, block, 0, stream>>>(in, out, total);
}

// Round 10
// 20.971 us; speedup vs baseline: 1.0665x; 1.0665x over previous
//
#include <hip/hip_runtime.h>

// MedianFilter2D: 3x3 median, reflect pad, [16,3,512,512] f32.
// R9: LDS-staged stencil via global_load_lds DMA (no dest-VGPR loads, no
// edge loads, no shuffles) + full store/load phase separation.
// Block = 512 cols x BR=16 out rows; stages SR=18 rows (36.9 KB) as 36 x 1KB
// DMA chunks (9 per wave, fire-and-forget), vmcnt(0)+barrier, then each
// thread computes 4 cols x 8 rows from LDS (halos = plain LDS reads) and
// NT-stores. Median: per-row sorted triple, then vertical med3 combine.

constexpr int Wd = 512;
constexpr int Hd = 512;
constexpr int BR = 16;           // output rows per block
constexpr int SR = BR + 2;       // staged rows (with vertical halo)

typedef float f32x4 __attribute__((ext_vector_type(4)));

__device__ __forceinline__ float med3f(float a, float b, float c) {
    return __builtin_amdgcn_fmed3f(a, b, c);
}
__device__ __forceinline__ float min3f(float a, float b, float c) {
    return fminf(fminf(a, b), c);   // v_min3_f32
}
__device__ __forceinline__ float max3f(float a, float b, float c) {
    return fmaxf(fmaxf(a, b), c);   // v_max3_f32
}

struct Trip { float mn[4], md[4], mx[4]; };

__global__ __launch_bounds__(256) void MedianFilter2D_68745246540291_kernel(
    const float* __restrict__ in, float* __restrict__ out) {
    __shared__ float lds[SR * Wd];          // 36,864 B

    int bid   = blockIdx.x;
    int tile  = bid & 31;                   // 32 row-tiles per plane
    long plane = (long)(bid >> 5);
    int r0    = tile * BR;

    const float* p = in  + plane * (long)(Hd * Wd);
    float*       q = out + plane * (long)(Hd * Wd);

    int tid  = threadIdx.x;
    int w    = tid >> 6;                    // wave id (0..3)
    int lane = tid & 63;

    // ---- stage phase: 36 chunks of 1 KB, wave w takes chunks w, w+4, ...
#pragma unroll
    for (int k = 0; k < 9; ++k) {
        int c  = k * 4 + w;                 // chunk id 0..35
        int s  = c >> 1;                    // staged row 0..17
        int hh = c & 1;                     // half: cols 0-255 / 256-511
        int g  = r0 - 1 + s;
        int h  = (g < 0) ? 1 : ((g > Hd - 1) ? Hd - 2 : g);   // reflect rows
        const float* src = p + (long)h * Wd + hh * 256 + lane * 4;  // per-lane
        float* dst = &lds[s * Wd + hh * 256];                 // wave-uniform
        __builtin_amdgcn_global_load_lds(
            (const __attribute__((address_space(1))) void*)src,
            (__attribute__((address_space(3))) void*)dst, 16, 0, 0);
    }
    asm volatile("s_waitcnt vmcnt(0)" ::: "memory");
    __syncthreads();

    // ---- compute phase: thread = 4-col group x 8 rows, all from LDS
    int cg = tid & 127;
    int w4 = cg << 2;
    int rh = tid >> 7;                      // 0 or 1
    int rbase = rh * 8;                     // local out-row base

    int lc = (w4 == 0)   ? 1   : w4 - 1;    // reflect col -1 -> 1
    int rc = (w4 == 508) ? 510 : w4 + 4;    // reflect col 512 -> 510

    auto mktrip = [&](int s) -> Trip {
        const float* row = &lds[s * Wd];
        f32x4 c4 = *reinterpret_cast<const f32x4*>(row + w4);
        float v[6] = { row[lc], c4.x, c4.y, c4.z, c4.w, row[rc] };
        Trip t;
#pragma unroll
        for (int j = 0; j < 4; ++j) {
            t.mn[j] = min3f(v[j], v[j + 1], v[j + 2]);
            t.md[j] = med3f(v[j], v[j + 1], v[j + 2]);
            t.mx[j] = max3f(v[j], v[j + 1], v[j + 2]);
        }
        return t;
    };

    Trip t0 = mktrip(rbase);                // staged row s == global r0+rbase-1+s? see map
    Trip t1 = mktrip(rbase + 1);
#pragma unroll
    for (int i = 0; i < 8; ++i) {
        Trip t2 = mktrip(rbase + i + 2);    // staged s = local row + 1 halo offset
        f32x4 o;
#pragma unroll
        for (int j = 0; j < 4; ++j) {
            float lo = max3f(t0.mn[j], t1.mn[j], t2.mn[j]);
            float mi = med3f(t0.md[j], t1.md[j], t2.md[j]);
            float hi = min3f(t0.mx[j], t1.mx[j], t2.mx[j]);
            o[j] = med3f(lo, mi, hi);
        }
        __builtin_nontemporal_store(o, reinterpret_cast<f32x4*>(
            q + (long)(r0 + rbase + i) * Wd + w4));
        t0 = t1;
        t1 = t2;
    }
}

extern "C" void kernel_launch(void* const* d_in, const int* in_sizes, int n_in,
                              void* d_out, int out_size, void* d_ws, size_t ws_size,
                              hipStream_t stream) {
    const float* in = (const float*)d_in[0];
    float* out = (float*)d_out;
    int grid = out_size / (Wd * BR);        // 1536 blocks (48 planes x 32 tiles)
    MedianFilter2D_68745246540291_kernel<<<grid, 256, 0, stream>>>(in, out);
}

// Round 11
// 20.792 us; speedup vs baseline: 1.0757x; 1.0086x over previous
//
#include <hip/hip_runtime.h>

// MedianFilter2D: 3x3 median, reflect pad, [16,3,512,512] f32.
// R10: cross-tile pipelined LDS staging. Block = 512 cols x 32 out rows
// (two 16-row tiles, one 34-row LDS buffer, 69.6 KB, 2 blocks/CU).
//   stage A (18 rows, global_load_lds DMA) -> vmcnt(0)+barrier
//   issue  B (16 rows, fire-and-forget)    -> compute+NT-store tile A
//   vmcnt(0)+barrier                       -> compute+NT-store tile B
// Tile B's stage latency hides under tile A's compute; halo rows staged
// once per block (read amp 34/32 = 1.0625x, ~103.7 MB total traffic).

constexpr int Wd = 512;
constexpr int Hd = 512;
constexpr int BR = 16;            // rows per tile
constexpr int SR = 2 * BR + 2;    // 34 staged rows per block

typedef float f32x4 __attribute__((ext_vector_type(4)));

__device__ __forceinline__ float med3f(float a, float b, float c) {
    return __builtin_amdgcn_fmed3f(a, b, c);
}
__device__ __forceinline__ float min3f(float a, float b, float c) {
    return fminf(fminf(a, b), c);   // v_min3_f32
}
__device__ __forceinline__ float max3f(float a, float b, float c) {
    return fmaxf(fmaxf(a, b), c);   // v_max3_f32
}

struct Trip { float mn[4], md[4], mx[4]; };

__global__ __launch_bounds__(256) void MedianFilter2D_68745246540291_kernel(
    const float* __restrict__ in, float* __restrict__ out) {
    __shared__ float lds[SR * Wd];          // 69,632 B

    int bid = blockIdx.x;
    int r0  = (bid & 15) * (2 * BR);        // 16 double-tiles per plane
    long plane = (long)(bid >> 4);

    const float* p = in  + plane * (long)(Hd * Wd);
    float*       q = out + plane * (long)(Hd * Wd);

    int tid  = threadIdx.x;
    int w    = tid >> 6;                    // wave id (0..3)
    int lane = tid & 63;

    // one chunk = half a row (256 floats = 1 KB); staged row s <- global row r0-1+s
    auto stage_chunk = [&](int c) {
        int s  = c >> 1;
        int hh = c & 1;
        int g  = r0 - 1 + s;
        int h  = (g < 0) ? 1 : ((g > Hd - 1) ? Hd - 2 : g);   // reflect rows
        const float* src = p + (long)h * Wd + hh * 256 + lane * 4;   // per-lane
        float* dst = &lds[s * Wd + hh * 256];                        // wave-uniform
        __builtin_amdgcn_global_load_lds(
            (const __attribute__((address_space(1))) void*)src,
            (__attribute__((address_space(3))) void*)dst, 16, 0, 0);
    };

    // ---- stage tile A: staged rows 0..17 (chunks 0..35)
#pragma unroll
    for (int k = 0; k < 9; ++k) stage_chunk(k * 4 + w);
    asm volatile("s_waitcnt vmcnt(0)" ::: "memory");
    __syncthreads();

    // ---- issue tile B stages: staged rows 18..33 (chunks 36..67), no wait
#pragma unroll
    for (int k = 0; k < 8; ++k) stage_chunk(36 + k * 4 + w);

    // ---- compute mapping: thread = 4-col group x 8 rows per tile
    int cg = tid & 127;
    int w4 = cg << 2;
    int rh = tid >> 7;                      // 0 or 1 (row half of tile)
    int lc = (w4 == 0)   ? 1   : w4 - 1;    // reflect col -1 -> 1
    int rc = (w4 == 508) ? 510 : w4 + 4;    // reflect col 512 -> 510

    auto mktrip = [&](int s) -> Trip {
        const float* row = &lds[s * Wd];
        f32x4 c4 = *reinterpret_cast<const f32x4*>(row + w4);
        float v[6] = { row[lc], c4.x, c4.y, c4.z, c4.w, row[rc] };
        Trip t;
#pragma unroll
        for (int j = 0; j < 4; ++j) {
            t.mn[j] = min3f(v[j], v[j + 1], v[j + 2]);
            t.md[j] = med3f(v[j], v[j + 1], v[j + 2]);
            t.mx[j] = max3f(v[j], v[j + 1], v[j + 2]);
        }
        return t;
    };
    // out row orow0+i uses staged rows sbase+i .. sbase+i+2
    auto compute_tile = [&](int sbase, int orow0) {
        Trip t0 = mktrip(sbase);
        Trip t1 = mktrip(sbase + 1);
#pragma unroll
        for (int i = 0; i < 8; ++i) {
            Trip t2 = mktrip(sbase + i + 2);
            f32x4 o;
#pragma unroll
            for (int j = 0; j < 4; ++j) {
                float lo = max3f(t0.mn[j], t1.mn[j], t2.mn[j]);
                float mi = med3f(t0.md[j], t1.md[j], t2.md[j]);
                float hi = min3f(t0.mx[j], t1.mx[j], t2.mx[j]);
                o[j] = med3f(lo, mi, hi);
            }
            __builtin_nontemporal_store(o, reinterpret_cast<f32x4*>(
                q + (long)(orow0 + i) * Wd + w4));
            t0 = t1;
            t1 = t2;
        }
    };

    // tile A (staged rows 0..17), overlapped with tile B's DMA
    compute_tile(rh * 8, r0 + rh * 8);

    asm volatile("s_waitcnt vmcnt(0)" ::: "memory");
    __syncthreads();

    // tile B (staged rows 16..33)
    compute_tile(16 + rh * 8, r0 + 16 + rh * 8);
}

extern "C" void kernel_launch(void* const* d_in, const int* in_sizes, int n_in,
                              void* d_out, int out_size, void* d_ws, size_t ws_size,
                              hipStream_t stream) {
    const float* in = (const float*)d_in[0];
    float* out = (float*)d_out;
    int grid = out_size / (Wd * 2 * BR);    // 768 blocks (48 planes x 16)
    MedianFilter2D_68745246540291_kernel<<<grid, 256, 0, stream>>>(in, out);
}